// Round 1
// baseline (615.762 us; speedup 1.0000x reference)
//
#include <hip/hip_runtime.h>
#include <math.h>

// Problem constants
#define B_DIM 8
#define T_DIM 4096
#define K_DIM 1024   // IN_DIM
#define H_DIM 1024   // HIDDEN
#define M_DIM (B_DIM * T_DIM)   // 32768 rows

#define CH 64               // scan chunk length
#define NC (T_DIM / CH)     // 64 chunks per channel

typedef short bf16x8 __attribute__((ext_vector_type(8)));   // 8 bf16 = 4 VGPRs
typedef float f32x4  __attribute__((ext_vector_type(4)));

// ---------- helpers ----------
__device__ __forceinline__ unsigned short f2bf(float f) {
  unsigned int u = __builtin_bit_cast(unsigned int, f);
  u += 0x7FFFu + ((u >> 16) & 1u);   // round-to-nearest-even
  return (unsigned short)(u >> 16);
}

__device__ __forceinline__ void gload_lds16(const void* g, void* l) {
  __builtin_amdgcn_global_load_lds(
      (const __attribute__((address_space(1))) unsigned int*)g,
      (__attribute__((address_space(3))) unsigned int*)l,
      16 /*bytes, literal*/, 0 /*offset*/, 0 /*aux*/);
}

__device__ __forceinline__ float softplusf(float x) {
  return fmaxf(x, 0.f) + log1pf(__expf(-fabsf(x)));
}

// ---------- f32 -> bf16 convert (8 elems/thread) ----------
__global__ __launch_bounds__(256) void k_cvt(const float* __restrict__ in,
                                             unsigned short* __restrict__ out,
                                             int n8) {
  int i = blockIdx.x * 256 + threadIdx.x;
  if (i >= n8) return;
  float4 v0 = ((const float4*)in)[i * 2 + 0];
  float4 v1 = ((const float4*)in)[i * 2 + 1];
  bf16x8 r;
  r[0] = (short)f2bf(v0.x); r[1] = (short)f2bf(v0.y);
  r[2] = (short)f2bf(v0.z); r[3] = (short)f2bf(v0.w);
  r[4] = (short)f2bf(v1.x); r[5] = (short)f2bf(v1.y);
  r[6] = (short)f2bf(v1.z); r[7] = (short)f2bf(v1.w);
  ((bf16x8*)out)[i] = r;
}

// ---------- dual GEMM: z1 = x@Wd^T, z2 = x@Wb^T; epilogue -> a_t, b_t ----------
// 128x128 tile, BK=32, 4 waves (2x2), each wave 64x64 out, 16x16x32 bf16 MFMA.
__global__ __launch_bounds__(256) void k_gemm_dual(
    const unsigned short* __restrict__ Xb,    // [M][K] bf16 bits
    const unsigned short* __restrict__ Wdb,   // [H][K] bf16 bits
    const unsigned short* __restrict__ Wbb,   // [H][K] bf16 bits
    const float* __restrict__ bd,
    const float* __restrict__ bb,
    const float* __restrict__ A_log,
    float* __restrict__ a_out,                // [M][H]
    float* __restrict__ b_out)                // [M][H] (aliases d_out)
{
  __shared__ unsigned short As [128 * 32];   // 8 KiB
  __shared__ unsigned short Bs0[128 * 32];   // 8 KiB
  __shared__ unsigned short Bs1[128 * 32];   // 8 KiB

  const int tid  = threadIdx.x;
  const int bm   = blockIdx.x * 128;
  const int bn   = blockIdx.y * 128;
  const int w    = tid >> 6;
  const int lane = tid & 63;
  const int wm   = (w >> 1) * 64;
  const int wn   = (w & 1) * 64;

  f32x4 accd[4][4], accb[4][4];
  const f32x4 z4 = {0.f, 0.f, 0.f, 0.f};
  for (int m = 0; m < 4; m++)
    for (int n = 0; n < 4; n++) { accd[m][n] = z4; accb[m][n] = z4; }

  const int fr = lane & 15;
  const int kq = (lane >> 4) * 8;

  for (int k0 = 0; k0 < K_DIM; k0 += 32) {
    // stage A, Bd, Bb tiles: 2 x 16B chunks per thread per tile
#pragma unroll
    for (int i = 0; i < 2; i++) {
      int idx = i * 256 + tid;          // 16B chunk id, 0..511
      int row = idx >> 2;               // 0..127
      int kk  = (idx & 3) * 8;          // 0,8,16,24 (bf16 elems)
      size_t goffA = (size_t)(bm + row) * K_DIM + (size_t)(k0 + kk);
      size_t goffB = (size_t)(bn + row) * K_DIM + (size_t)(k0 + kk);
      gload_lds16(Xb  + goffA, &As [row * 32 + kk]);
      gload_lds16(Wdb + goffB, &Bs0[row * 32 + kk]);
      gload_lds16(Wbb + goffB, &Bs1[row * 32 + kk]);
    }
    __syncthreads();

    bf16x8 af[4], b0[4], b1[4];
#pragma unroll
    for (int m = 0; m < 4; m++)
      af[m] = *(const bf16x8*)&As[(wm + m * 16 + fr) * 32 + kq];
#pragma unroll
    for (int n = 0; n < 4; n++) {
      b0[n] = *(const bf16x8*)&Bs0[(wn + n * 16 + fr) * 32 + kq];
      b1[n] = *(const bf16x8*)&Bs1[(wn + n * 16 + fr) * 32 + kq];
    }
#pragma unroll
    for (int m = 0; m < 4; m++)
#pragma unroll
      for (int n = 0; n < 4; n++) {
        accd[m][n] = __builtin_amdgcn_mfma_f32_16x16x32_bf16(af[m], b0[n], accd[m][n], 0, 0, 0);
        accb[m][n] = __builtin_amdgcn_mfma_f32_16x16x32_bf16(af[m], b1[n], accb[m][n], 0, 0, 0);
      }
    __syncthreads();
  }

  // epilogue: C/D layout col = lane&15, row = (lane>>4)*4 + r  [m89-verified]
  const int col   = lane & 15;
  const int rbase = (lane >> 4) * 4;
#pragma unroll
  for (int n = 0; n < 4; n++) {
    int gn = bn + wn + n * 16 + col;
    float bdv = bd[gn];
    float bbv = bb[gn];
    float Ah  = __expf(A_log[gn]);
#pragma unroll
    for (int m = 0; m < 4; m++) {
#pragma unroll
      for (int r = 0; r < 4; r++) {
        int gm = bm + wm + m * 16 + rbase + r;
        float z1  = accd[m][n][r] + bdv;
        float z2  = accb[m][n][r] + bbv;
        float dlt = softplusf(z1);
        float av  = __expf(-dlt * Ah);
        size_t off = (size_t)gm * H_DIM + (size_t)gn;
        a_out[off] = av;
        b_out[off] = dlt * z2;
      }
    }
  }
}

// ---------- scan pass 1: per-chunk affine aggregates ----------
// thread idx = (b*NC + c)*H + h ; consecutive lanes = consecutive h (coalesced)
__global__ __launch_bounds__(256) void k_scan_agg(
    const float* __restrict__ a_arr, const float* b_arr,
    float* __restrict__ aggA, float* __restrict__ aggB)
{
  int idx = blockIdx.x * 256 + threadIdx.x;
  int h   = idx & (H_DIM - 1);
  int bc  = idx >> 10;              // b*NC + c
  int c   = bc & (NC - 1);
  int b   = bc >> 6;
  size_t base = ((size_t)b * T_DIM + (size_t)c * CH) * H_DIM + (size_t)h;
  float A = 1.f, Bv = 0.f;
#pragma unroll 8
  for (int i = 0; i < CH; i++) {
    float at = a_arr[base + (size_t)i * H_DIM];
    float bt = b_arr[base + (size_t)i * H_DIM];
    Bv = fmaf(at, Bv, bt);          // compose: (A,B) then (at,bt)
    A *= at;
  }
  aggA[idx] = A;
  aggB[idx] = Bv;
}

// ---------- scan pass 2: sequential scan over chunk aggregates ----------
__global__ __launch_bounds__(256) void k_scan_chunks(
    const float* __restrict__ aggA, const float* __restrict__ aggB,
    const float* __restrict__ h0, float* __restrict__ hstart)
{
  int idx = blockIdx.x * 256 + threadIdx.x;   // b*H + h
  int h   = idx & (H_DIM - 1);
  int b   = idx >> 10;
  float hc = h0[idx];
  for (int c = 0; c < NC; c++) {
    size_t o = ((size_t)(b * NC + c) << 10) + (size_t)h;
    hstart[o] = hc;
    hc = fmaf(aggA[o], hc, aggB[o]);
  }
}

// ---------- scan pass 3: re-apply within chunk + tanh ----------
__global__ __launch_bounds__(256) void k_scan_apply(
    const float* __restrict__ a_arr, const float* b_arr,
    const float* __restrict__ hstart, float* out)   // b_arr aliases out!
{
  int idx = blockIdx.x * 256 + threadIdx.x;
  int h   = idx & (H_DIM - 1);
  int bc  = idx >> 10;
  int c   = bc & (NC - 1);
  int b   = bc >> 6;
  size_t base = ((size_t)b * T_DIM + (size_t)c * CH) * H_DIM + (size_t)h;
  float hc = hstart[idx];
#pragma unroll 4
  for (int i = 0; i < CH; i++) {
    size_t o = base + (size_t)i * H_DIM;
    float at = a_arr[o];
    float bt = b_arr[o];       // read BEFORE the aliased write below
    hc = fmaf(at, hc, bt);
    out[o] = tanhf(hc);
  }
}

// ---------- launch ----------
extern "C" void kernel_launch(void* const* d_in, const int* in_sizes, int n_in,
                              void* d_out, int out_size, void* d_ws, size_t ws_size,
                              hipStream_t stream) {
  const float* x     = (const float*)d_in[0];
  const float* h0    = (const float*)d_in[1];
  const float* Wd    = (const float*)d_in[2];
  const float* bd    = (const float*)d_in[3];
  const float* Wb    = (const float*)d_in[4];
  const float* bb    = (const float*)d_in[5];
  const float* A_log = (const float*)d_in[6];
  float* out = (float*)d_out;

  char* ws = (char*)d_ws;
  unsigned short* xb   = (unsigned short*)(ws + 0);           //  64 MiB
  unsigned short* wdb  = (unsigned short*)(ws + 67108864);    //   2 MiB
  unsigned short* wbb  = (unsigned short*)(ws + 69206016);    //   2 MiB
  float*          aarr = (float*)(ws + 71303168);             // 128 MiB
  float*          aggA = (float*)(ws + 205520896);            //   2 MiB
  float*          aggB = (float*)(ws + 207618048);            //   2 MiB
  float*          hst  = (float*)(ws + 209715200);            //   2 MiB
  float*          barr = out;  // b_t staged in d_out, overwritten by k_scan_apply

  // converts
  k_cvt<<<(M_DIM * K_DIM / 8) / 256, 256, 0, stream>>>(x, xb, M_DIM * K_DIM / 8);
  k_cvt<<<(H_DIM * K_DIM / 8) / 256, 256, 0, stream>>>(Wd, wdb, H_DIM * K_DIM / 8);
  k_cvt<<<(H_DIM * K_DIM / 8) / 256, 256, 0, stream>>>(Wb, wbb, H_DIM * K_DIM / 8);

  // fused dual GEMM + nonlinearity epilogue
  dim3 gg(M_DIM / 128, H_DIM / 128);
  k_gemm_dual<<<gg, 256, 0, stream>>>(xb, wdb, wbb, bd, bb, A_log, aarr, barr);

  // chunked affine scan over T
  k_scan_agg   <<<(B_DIM * NC * H_DIM) / 256, 256, 0, stream>>>(aarr, barr, aggA, aggB);
  k_scan_chunks<<<(B_DIM * H_DIM) / 256,      256, 0, stream>>>(aggA, aggB, h0, hst);
  k_scan_apply <<<(B_DIM * NC * H_DIM) / 256, 256, 0, stream>>>(aarr, barr, hst, out);
}

// Round 2
// 364.310 us; speedup vs baseline: 1.6902x; 1.6902x over previous
//
#include <hip/hip_runtime.h>
#include <math.h>

// Problem constants
#define B_DIM 8
#define T_DIM 4096
#define K_DIM 1024   // IN_DIM
#define H_DIM 1024   // HIDDEN
#define M_DIM (B_DIM * T_DIM)   // 32768 rows

#define CH 64               // scan chunk length
#define NC (T_DIM / CH)     // 64 chunks per channel

typedef short bf16x8 __attribute__((ext_vector_type(8)));   // 8 bf16 = 4 VGPRs
typedef float f32x4  __attribute__((ext_vector_type(4)));

// ---------- helpers ----------
__device__ __forceinline__ unsigned short f2bf(float f) {
  unsigned int u = __builtin_bit_cast(unsigned int, f);
  u += 0x7FFFu + ((u >> 16) & 1u);   // round-to-nearest-even
  return (unsigned short)(u >> 16);
}

__device__ __forceinline__ void gload_lds16(const void* g, void* l) {
  __builtin_amdgcn_global_load_lds(
      (const __attribute__((address_space(1))) unsigned int*)g,
      (__attribute__((address_space(3))) unsigned int*)l,
      16 /*bytes, literal*/, 0 /*offset*/, 0 /*aux*/);
}

// fast softplus: v_exp_f32 + v_log_f32 (≈1e-6 rel err, vs log1pf libcall)
__device__ __forceinline__ float softplus_fast(float x) {
  float e = __expf(-fabsf(x));
  return fmaxf(x, 0.f) + __logf(1.f + e);
}

// fast tanh: 1 - 2/(e^{2x}+1). e=inf -> 1, e=0 -> -1 (correct saturation).
__device__ __forceinline__ float tanh_fast(float x) {
  float e = __expf(2.f * x);
  return 1.f - 2.f * __builtin_amdgcn_rcpf(e + 1.f);
}

// ---------- f32 -> bf16 convert (8 elems/thread) ----------
__global__ __launch_bounds__(256) void k_cvt(const float* __restrict__ in,
                                             unsigned short* __restrict__ out,
                                             int n8) {
  int i = blockIdx.x * 256 + threadIdx.x;
  if (i >= n8) return;
  float4 v0 = ((const float4*)in)[i * 2 + 0];
  float4 v1 = ((const float4*)in)[i * 2 + 1];
  bf16x8 r;
  r[0] = (short)f2bf(v0.x); r[1] = (short)f2bf(v0.y);
  r[2] = (short)f2bf(v0.z); r[3] = (short)f2bf(v0.w);
  r[4] = (short)f2bf(v1.x); r[5] = (short)f2bf(v1.y);
  r[6] = (short)f2bf(v1.z); r[7] = (short)f2bf(v1.w);
  ((bf16x8*)out)[i] = r;
}

// ---------- dual GEMM: z1 = x@Wd^T, z2 = x@Wb^T; epilogue -> a_t, b_t ----------
// 128x128 tile, BK=32, 8 waves (2x4), each wave 64x32 dual out, 16x16x32 bf16 MFMA.
// 512 threads halves per-lane accumulator (64 f32) vs R0 -> 4 waves/SIMD occupancy.
__global__ __launch_bounds__(512, 4) void k_gemm_dual(
    const unsigned short* __restrict__ Xb,    // [M][K] bf16 bits
    const unsigned short* __restrict__ Wdb,   // [H][K] bf16 bits
    const unsigned short* __restrict__ Wbb,   // [H][K] bf16 bits
    const float* __restrict__ bd,
    const float* __restrict__ bb,
    const float* __restrict__ A_log,
    float* __restrict__ a_out,                // [M][H]
    float* __restrict__ b_out)                // [M][H] (aliases d_out)
{
  __shared__ unsigned short As [128 * 32];   // 8 KiB
  __shared__ unsigned short Bs0[128 * 32];   // 8 KiB
  __shared__ unsigned short Bs1[128 * 32];   // 8 KiB

  const int tid  = threadIdx.x;
  const int bm   = blockIdx.x * 128;
  const int bn   = blockIdx.y * 128;
  const int w    = tid >> 6;
  const int lane = tid & 63;
  const int wm   = (w >> 2) * 64;    // 2 wave-rows
  const int wn   = (w & 3) * 32;     // 4 wave-cols

  f32x4 accd[4][2], accb[4][2];
  const f32x4 z4 = {0.f, 0.f, 0.f, 0.f};
  for (int m = 0; m < 4; m++)
    for (int n = 0; n < 2; n++) { accd[m][n] = z4; accb[m][n] = z4; }

  const int fr = lane & 15;
  const int kq = (lane >> 4) * 8;

  // staging: 512 threads x 16B = one full 128x32 bf16 tile per issue
  const int srow = tid >> 2;          // 0..127
  const int skk  = (tid & 3) * 8;     // 0,8,16,24

  for (int k0 = 0; k0 < K_DIM; k0 += 32) {
    size_t goffA = (size_t)(bm + srow) * K_DIM + (size_t)(k0 + skk);
    size_t goffB = (size_t)(bn + srow) * K_DIM + (size_t)(k0 + skk);
    gload_lds16(Xb  + goffA, &As [srow * 32 + skk]);
    gload_lds16(Wdb + goffB, &Bs0[srow * 32 + skk]);
    gload_lds16(Wbb + goffB, &Bs1[srow * 32 + skk]);
    __syncthreads();

    bf16x8 af[4], b0[2], b1[2];
#pragma unroll
    for (int m = 0; m < 4; m++)
      af[m] = *(const bf16x8*)&As[(wm + m * 16 + fr) * 32 + kq];
#pragma unroll
    for (int n = 0; n < 2; n++) {
      b0[n] = *(const bf16x8*)&Bs0[(wn + n * 16 + fr) * 32 + kq];
      b1[n] = *(const bf16x8*)&Bs1[(wn + n * 16 + fr) * 32 + kq];
    }
#pragma unroll
    for (int m = 0; m < 4; m++)
#pragma unroll
      for (int n = 0; n < 2; n++) {
        accd[m][n] = __builtin_amdgcn_mfma_f32_16x16x32_bf16(af[m], b0[n], accd[m][n], 0, 0, 0);
        accb[m][n] = __builtin_amdgcn_mfma_f32_16x16x32_bf16(af[m], b1[n], accb[m][n], 0, 0, 0);
      }
    __syncthreads();
  }

  // epilogue: C/D layout col = lane&15, row = (lane>>4)*4 + r  [m89-verified]
  const int col   = lane & 15;
  const int rbase = (lane >> 4) * 4;
#pragma unroll
  for (int n = 0; n < 2; n++) {
    int gn = bn + wn + n * 16 + col;
    float bdv = bd[gn];
    float bbv = bb[gn];
    float Ah  = __expf(A_log[gn]);
#pragma unroll
    for (int m = 0; m < 4; m++) {
#pragma unroll
      for (int r = 0; r < 4; r++) {
        int gm = bm + wm + m * 16 + rbase + r;
        float z1  = accd[m][n][r] + bdv;
        float z2  = accb[m][n][r] + bbv;
        float dlt = softplus_fast(z1);
        float av  = __expf(-dlt * Ah);
        size_t off = (size_t)gm * H_DIM + (size_t)gn;
        a_out[off] = av;
        b_out[off] = dlt * z2;
      }
    }
  }
}

// ---------- scan pass 1: per-chunk affine aggregates ----------
__global__ __launch_bounds__(256) void k_scan_agg(
    const float* __restrict__ a_arr, const float* b_arr,
    float* __restrict__ aggA, float* __restrict__ aggB)
{
  int idx = blockIdx.x * 256 + threadIdx.x;
  int h   = idx & (H_DIM - 1);
  int bc  = idx >> 10;              // b*NC + c
  int c   = bc & (NC - 1);
  int b   = bc >> 6;
  size_t base = ((size_t)b * T_DIM + (size_t)c * CH) * H_DIM + (size_t)h;
  float A = 1.f, Bv = 0.f;
#pragma unroll 8
  for (int i = 0; i < CH; i++) {
    float at = a_arr[base + (size_t)i * H_DIM];
    float bt = b_arr[base + (size_t)i * H_DIM];
    Bv = fmaf(at, Bv, bt);          // compose: (A,B) then (at,bt)
    A *= at;
  }
  aggA[idx] = A;
  aggB[idx] = Bv;
}

// ---------- scan pass 2: sequential scan over chunk aggregates ----------
__global__ __launch_bounds__(256) void k_scan_chunks(
    const float* __restrict__ aggA, const float* __restrict__ aggB,
    const float* __restrict__ h0, float* __restrict__ hstart)
{
  int idx = blockIdx.x * 256 + threadIdx.x;   // b*H + h
  int h   = idx & (H_DIM - 1);
  int b   = idx >> 10;
  float hc = h0[idx];
  for (int c = 0; c < NC; c++) {
    size_t o = ((size_t)(b * NC + c) << 10) + (size_t)h;
    hstart[o] = hc;
    hc = fmaf(aggA[o], hc, aggB[o]);
  }
}

// ---------- scan pass 3: re-apply within chunk + tanh ----------
__global__ __launch_bounds__(256) void k_scan_apply(
    const float* __restrict__ a_arr, const float* b_arr,
    const float* __restrict__ hstart, float* out)   // b_arr aliases out!
{
  int idx = blockIdx.x * 256 + threadIdx.x;
  int h   = idx & (H_DIM - 1);
  int bc  = idx >> 10;
  int c   = bc & (NC - 1);
  int b   = bc >> 6;
  size_t base = ((size_t)b * T_DIM + (size_t)c * CH) * H_DIM + (size_t)h;
  float hc = hstart[idx];
#pragma unroll 4
  for (int i = 0; i < CH; i++) {
    size_t o = base + (size_t)i * H_DIM;
    float at = a_arr[o];
    float bt = b_arr[o];       // read BEFORE the aliased write below
    hc = fmaf(at, hc, bt);
    out[o] = tanh_fast(hc);
  }
}

// ---------- launch ----------
extern "C" void kernel_launch(void* const* d_in, const int* in_sizes, int n_in,
                              void* d_out, int out_size, void* d_ws, size_t ws_size,
                              hipStream_t stream) {
  const float* x     = (const float*)d_in[0];
  const float* h0    = (const float*)d_in[1];
  const float* Wd    = (const float*)d_in[2];
  const float* bd    = (const float*)d_in[3];
  const float* Wb    = (const float*)d_in[4];
  const float* bb    = (const float*)d_in[5];
  const float* A_log = (const float*)d_in[6];
  float* out = (float*)d_out;

  char* ws = (char*)d_ws;
  unsigned short* xb   = (unsigned short*)(ws + 0);           //  64 MiB
  unsigned short* wdb  = (unsigned short*)(ws + 67108864);    //   2 MiB
  unsigned short* wbb  = (unsigned short*)(ws + 69206016);    //   2 MiB
  float*          aarr = (float*)(ws + 71303168);             // 128 MiB
  float*          aggA = (float*)(ws + 205520896);            //   2 MiB
  float*          aggB = (float*)(ws + 207618048);            //   2 MiB
  float*          hst  = (float*)(ws + 209715200);            //   2 MiB
  float*          barr = out;  // b_t staged in d_out, overwritten by k_scan_apply

  // converts
  k_cvt<<<(M_DIM * K_DIM / 8) / 256, 256, 0, stream>>>(x, xb, M_DIM * K_DIM / 8);
  k_cvt<<<(H_DIM * K_DIM / 8) / 256, 256, 0, stream>>>(Wd, wdb, H_DIM * K_DIM / 8);
  k_cvt<<<(H_DIM * K_DIM / 8) / 256, 256, 0, stream>>>(Wb, wbb, H_DIM * K_DIM / 8);

  // fused dual GEMM + nonlinearity epilogue
  dim3 gg(M_DIM / 128, H_DIM / 128);
  k_gemm_dual<<<gg, 512, 0, stream>>>(xb, wdb, wbb, bd, bb, A_log, aarr, barr);

  // chunked affine scan over T
  k_scan_agg   <<<(B_DIM * NC * H_DIM) / 256, 256, 0, stream>>>(aarr, barr, aggA, aggB);
  k_scan_chunks<<<(B_DIM * H_DIM) / 256,      256, 0, stream>>>(aggA, aggB, h0, hst);
  k_scan_apply <<<(B_DIM * NC * H_DIM) / 256, 256, 0, stream>>>(aarr, barr, hst, out);
}

// Round 3
// 337.020 us; speedup vs baseline: 1.8271x; 1.0810x over previous
//
#include <hip/hip_runtime.h>
#include <math.h>

// Problem constants
#define B_DIM 8
#define T_DIM 4096
#define K_DIM 1024   // IN_DIM
#define H_DIM 1024   // HIDDEN
#define M_DIM (B_DIM * T_DIM)   // 32768 rows

#define CH 64               // scan chunk length
#define NC (T_DIM / CH)     // 64 chunks per channel
#define BK 64               // GEMM K-step (128B rows -> full 8-slot XOR swizzle)

typedef short bf16x8 __attribute__((ext_vector_type(8)));   // 8 bf16 = 4 VGPRs
typedef float f32x4  __attribute__((ext_vector_type(4)));

// ---------- helpers ----------
__device__ __forceinline__ unsigned short f2bf(float f) {
  unsigned int u = __builtin_bit_cast(unsigned int, f);
  u += 0x7FFFu + ((u >> 16) & 1u);   // round-to-nearest-even
  return (unsigned short)(u >> 16);
}

__device__ __forceinline__ void gload_lds16(const void* g, void* l) {
  __builtin_amdgcn_global_load_lds(
      (const __attribute__((address_space(1))) unsigned int*)g,
      (__attribute__((address_space(3))) unsigned int*)l,
      16 /*bytes, literal*/, 0 /*offset*/, 0 /*aux*/);
}

// fast softplus: v_exp_f32 + v_log_f32
__device__ __forceinline__ float softplus_fast(float x) {
  float e = __expf(-fabsf(x));
  return fmaxf(x, 0.f) + __logf(1.f + e);
}

// fast tanh: 1 - 2/(e^{2x}+1). e=inf -> 1, e=0 -> -1 (correct saturation).
__device__ __forceinline__ float tanh_fast(float x) {
  float e = __expf(2.f * x);
  return 1.f - 2.f * __builtin_amdgcn_rcpf(e + 1.f);
}

// ---------- f32 -> bf16 convert (8 elems/thread) ----------
__global__ __launch_bounds__(256) void k_cvt(const float* __restrict__ in,
                                             unsigned short* __restrict__ out,
                                             int n8) {
  int i = blockIdx.x * 256 + threadIdx.x;
  if (i >= n8) return;
  float4 v0 = ((const float4*)in)[i * 2 + 0];
  float4 v1 = ((const float4*)in)[i * 2 + 1];
  bf16x8 r;
  r[0] = (short)f2bf(v0.x); r[1] = (short)f2bf(v0.y);
  r[2] = (short)f2bf(v0.z); r[3] = (short)f2bf(v0.w);
  r[4] = (short)f2bf(v1.x); r[5] = (short)f2bf(v1.y);
  r[6] = (short)f2bf(v1.z); r[7] = (short)f2bf(v1.w);
  ((bf16x8*)out)[i] = r;
}

// ---------- dual GEMM + nonlinearity + per-chunk affine aggregates ----------
// 128x128 tile, BK=64, 8 waves (2x4), wave = 64x32 dual output.
// LDS XOR-swizzle (T2): 16B chunk c at row r holds global chunk c^(r&7);
// gload_lds dest is LINEAR, global source pre-swizzled (rule 21 / m173).
// Epilogue additionally computes the CH=64 chunk affine aggregate per column
// (one wave's 64 rows == exactly one scan chunk) -> kills k_scan_agg kernel.
__global__ __launch_bounds__(512, 4) void k_gemm_dual(
    const unsigned short* __restrict__ Xb,    // [M][K] bf16 bits
    const unsigned short* __restrict__ Wdb,   // [H][K] bf16 bits
    const unsigned short* __restrict__ Wbb,   // [H][K] bf16 bits
    const float* __restrict__ bd,
    const float* __restrict__ bb,
    const float* __restrict__ A_log,
    float* __restrict__ a_out,                // [M][H]
    float* __restrict__ b_out,                // [M][H] (aliases d_out)
    float* __restrict__ aggA,                 // [B*NC][H]
    float* __restrict__ aggB)                 // [B*NC][H]
{
  __shared__ unsigned short As [128 * BK];   // 16 KiB
  __shared__ unsigned short Bs0[128 * BK];   // 16 KiB
  __shared__ unsigned short Bs1[128 * BK];   // 16 KiB

  const int tid  = threadIdx.x;
  const int bm   = blockIdx.x * 128;
  const int bn   = blockIdx.y * 128;
  const int w    = tid >> 6;
  const int lane = tid & 63;
  const int wm   = (w >> 2) * 64;    // 2 wave-rows
  const int wn   = (w & 3) * 32;     // 4 wave-cols

  f32x4 accd[4][2], accb[4][2];
  const f32x4 z4 = {0.f, 0.f, 0.f, 0.f};
  for (int m = 0; m < 4; m++)
    for (int n = 0; n < 2; n++) { accd[m][n] = z4; accb[m][n] = z4; }

  const int fr = lane & 15;
  const int hi = lane >> 4;

  for (int k0 = 0; k0 < K_DIM; k0 += BK) {
    // stage 3 tiles of 128x64 bf16 = 1024 chunks of 16B each, 2 per thread
#pragma unroll
    for (int i = 0; i < 2; i++) {
      int idx = i * 512 + tid;            // 16B chunk id, 0..1023
      int row = idx >> 3;                 // 0..127
      int cg  = (idx & 7) ^ (row & 7);    // pre-swizzled global chunk
      size_t goffA = (size_t)(bm + row) * K_DIM + (size_t)(k0 + cg * 8);
      size_t goffB = (size_t)(bn + row) * K_DIM + (size_t)(k0 + cg * 8);
      gload_lds16(Xb  + goffA, (char*)As  + idx * 16);
      gload_lds16(Wdb + goffB, (char*)Bs0 + idx * 16);
      gload_lds16(Wbb + goffB, (char*)Bs1 + idx * 16);
    }
    __syncthreads();

#pragma unroll
    for (int ks = 0; ks < 2; ks++) {
      bf16x8 af[4], b0[2], b1[2];
#pragma unroll
      for (int m = 0; m < 4; m++) {
        int row = wm + m * 16 + fr;
        int ch  = (ks * 4 + hi) ^ (row & 7);      // swizzled read chunk
        af[m] = *(const bf16x8*)&As[row * BK + ch * 8];
      }
#pragma unroll
      for (int n = 0; n < 2; n++) {
        int row = wn + n * 16 + fr;
        int ch  = (ks * 4 + hi) ^ (row & 7);
        b0[n] = *(const bf16x8*)&Bs0[row * BK + ch * 8];
        b1[n] = *(const bf16x8*)&Bs1[row * BK + ch * 8];
      }
#pragma unroll
      for (int m = 0; m < 4; m++)
#pragma unroll
        for (int n = 0; n < 2; n++) {
          accd[m][n] = __builtin_amdgcn_mfma_f32_16x16x32_bf16(af[m], b0[n], accd[m][n], 0, 0, 0);
          accb[m][n] = __builtin_amdgcn_mfma_f32_16x16x32_bf16(af[m], b1[n], accb[m][n], 0, 0, 0);
        }
    }
    __syncthreads();
  }

  // epilogue: C/D layout col = lane&15, row = (lane>>4)*4 + r  [m89-verified]
  const int col    = lane & 15;
  const int rbase  = hi * 4;
  const int bidx   = bm >> 12;                          // batch (T=4096)
  const int cchunk = ((bm & (T_DIM - 1)) + wm) >> 6;    // scan chunk id

#pragma unroll
  for (int n = 0; n < 2; n++) {
    int gn = bn + wn + n * 16 + col;
    float bdv = bd[gn];
    float bbv = bb[gn];
    float Ah  = __expf(A_log[gn]);
    float segA[4], segB[4];
#pragma unroll
    for (int m = 0; m < 4; m++) {
      float sA = 1.f, sB = 0.f;
#pragma unroll
      for (int r = 0; r < 4; r++) {
        int gm = bm + wm + m * 16 + rbase + r;
        float z1  = accd[m][n][r] + bdv;
        float z2  = accb[m][n][r] + bbv;
        float dlt = softplus_fast(z1);
        float av  = __expf(-dlt * Ah);
        float bv  = dlt * z2;
        size_t off = (size_t)gm * H_DIM + (size_t)gn;
        a_out[off] = av;
        b_out[off] = bv;
        sB = fmaf(av, sB, bv);     // compose in ascending t within 4-row run
        sA *= av;
      }
      segA[m] = sA; segB[m] = sB;
    }
    // ordered cross-lane compose: t order = m-major, then hi, then r
    float chA = 1.f, chB = 0.f;
#pragma unroll
    for (int m = 0; m < 4; m++) {
#pragma unroll
      for (int h2 = 0; h2 < 4; h2++) {
        float sa = __shfl(segA[m], col + h2 * 16, 64);
        float sb = __shfl(segB[m], col + h2 * 16, 64);
        chB = fmaf(sa, chB, sb);
        chA *= sa;
      }
    }
    if (lane < 16) {
      size_t o = ((size_t)(bidx * NC + cchunk) << 10) + (size_t)gn;
      aggA[o] = chA;
      aggB[o] = chB;
    }
  }
}

// ---------- scan pass 2: sequential scan over chunk aggregates ----------
__global__ __launch_bounds__(256) void k_scan_chunks(
    const float* __restrict__ aggA, const float* __restrict__ aggB,
    const float* __restrict__ h0, float* __restrict__ hstart)
{
  int idx = blockIdx.x * 256 + threadIdx.x;   // b*H + h
  int h   = idx & (H_DIM - 1);
  int b   = idx >> 10;
  float hc = h0[idx];
  for (int c = 0; c < NC; c++) {
    size_t o = ((size_t)(b * NC + c) << 10) + (size_t)h;
    hstart[o] = hc;
    hc = fmaf(aggA[o], hc, aggB[o]);
  }
}

// ---------- scan pass 3: re-apply within chunk + tanh ----------
__global__ __launch_bounds__(256) void k_scan_apply(
    const float* __restrict__ a_arr, const float* b_arr,
    const float* __restrict__ hstart, float* out)   // b_arr aliases out!
{
  int idx = blockIdx.x * 256 + threadIdx.x;
  int h   = idx & (H_DIM - 1);
  int bc  = idx >> 10;
  int c   = bc & (NC - 1);
  int b   = bc >> 6;
  size_t base = ((size_t)b * T_DIM + (size_t)c * CH) * H_DIM + (size_t)h;
  float hc = hstart[idx];
#pragma unroll 4
  for (int i = 0; i < CH; i++) {
    size_t o = base + (size_t)i * H_DIM;
    float at = a_arr[o];
    float bt = b_arr[o];       // read BEFORE the aliased write below
    hc = fmaf(at, hc, bt);
    out[o] = tanh_fast(hc);
  }
}

// ---------- launch ----------
extern "C" void kernel_launch(void* const* d_in, const int* in_sizes, int n_in,
                              void* d_out, int out_size, void* d_ws, size_t ws_size,
                              hipStream_t stream) {
  const float* x     = (const float*)d_in[0];
  const float* h0    = (const float*)d_in[1];
  const float* Wd    = (const float*)d_in[2];
  const float* bd    = (const float*)d_in[3];
  const float* Wb    = (const float*)d_in[4];
  const float* bb    = (const float*)d_in[5];
  const float* A_log = (const float*)d_in[6];
  float* out = (float*)d_out;

  char* ws = (char*)d_ws;
  unsigned short* xb   = (unsigned short*)(ws + 0);           //  64 MiB
  unsigned short* wdb  = (unsigned short*)(ws + 67108864);    //   2 MiB
  unsigned short* wbb  = (unsigned short*)(ws + 69206016);    //   2 MiB
  float*          aarr = (float*)(ws + 71303168);             // 128 MiB
  float*          aggA = (float*)(ws + 205520896);            //   2 MiB
  float*          aggB = (float*)(ws + 207618048);            //   2 MiB
  float*          hst  = (float*)(ws + 209715200);            //   2 MiB
  float*          barr = out;  // b_t staged in d_out, overwritten by k_scan_apply

  // converts
  k_cvt<<<(M_DIM * K_DIM / 8) / 256, 256, 0, stream>>>(x, xb, M_DIM * K_DIM / 8);
  k_cvt<<<(H_DIM * K_DIM / 8) / 256, 256, 0, stream>>>(Wd, wdb, H_DIM * K_DIM / 8);
  k_cvt<<<(H_DIM * K_DIM / 8) / 256, 256, 0, stream>>>(Wb, wbb, H_DIM * K_DIM / 8);

  // fused dual GEMM + nonlinearity + chunk-aggregate epilogue
  dim3 gg(M_DIM / 128, H_DIM / 128);
  k_gemm_dual<<<gg, 512, 0, stream>>>(xb, wdb, wbb, bd, bb, A_log,
                                      aarr, barr, aggA, aggB);

  // chunked affine scan over T (agg pass now fused into GEMM)
  k_scan_chunks<<<(B_DIM * H_DIM) / 256,      256, 0, stream>>>(aggA, aggB, h0, hst);
  k_scan_apply <<<(B_DIM * NC * H_DIM) / 256, 256, 0, stream>>>(aarr, barr, hst, out);
}